// Round 4
// baseline (398.960 us; speedup 1.0000x reference)
//
#include <hip/hip_runtime.h>

#define P1 254   // pooled size after C1+S2
#define P2 125   // pooled size after C3+S4
#define C5_K 250000           // 16*125*125
#define C5_K4 62500           // in float4
#define C5_CHUNK_F4 1250      // 50 chunks per row
#define F6_OUT 98304
#define F6_RPB 128
#define F6_NBLK (F6_OUT / F6_RPB)   // 768
#define F6_STRIDE 124

// ---- ws layout (floats) ----
#define WS_H2   0        // 6*254*254 = 387096
#define WS_H4   400000   // 16*125*125 = 250000
#define WS_C5   650000   // 120
#define WS_PART 800000   // 768*64
#define WS_CNT  860000   // 1 uint

// C1 conv 5x5 (1->6) + ReLU + 2x2 avgpool, fused. One thread per pooled output.
// Block 0 also seeds the c5 accumulator with b5 and zeroes the f6f7 counter.
__global__ __launch_bounds__(256) void c1_s2_kernel(const float* __restrict__ x,
        const float* __restrict__ W1, const float* __restrict__ b1,
        float* __restrict__ h2,
        const float* __restrict__ b5,
        float* __restrict__ c5acc, unsigned int* __restrict__ counter) {
    if (blockIdx.x == 0) {
        int t = threadIdx.x;
        if (t < 120) c5acc[t] = b5[t];
        if (t == 128) counter[0] = 0u;
    }
    int t = blockIdx.x * 256 + threadIdx.x;
    const int total = 6 * P1 * P1;
    if (t >= total) return;
    int c  = t / (P1 * P1);
    int r  = t % (P1 * P1);
    int y  = r / P1, x0 = r % P1;

    float w[25];
    #pragma unroll
    for (int k = 0; k < 25; ++k) w[k] = W1[c * 25 + k];

    float p[6][6];
    const float2* xin2 = (const float2*)(x + (2 * y) * 512 + 2 * x0);  // 8B-aligned
    #pragma unroll
    for (int i = 0; i < 6; ++i) {
        float2 a0 = xin2[i * 256 + 0];
        float2 a1 = xin2[i * 256 + 1];
        float2 a2 = xin2[i * 256 + 2];
        p[i][0] = a0.x; p[i][1] = a0.y; p[i][2] = a1.x;
        p[i][3] = a1.y; p[i][4] = a2.x; p[i][5] = a2.y;
    }

    float bias = b1[c];
    float s = 0.f;
    #pragma unroll
    for (int dy = 0; dy < 2; ++dy)
        #pragma unroll
        for (int dx = 0; dx < 2; ++dx) {
            float a = bias;
            #pragma unroll
            for (int kh = 0; kh < 5; ++kh)
                #pragma unroll
                for (int kw = 0; kw < 5; ++kw)
                    a = fmaf(p[dy + kh][dx + kw], w[kh * 5 + kw], a);
            s += fmaxf(a, 0.f);
        }
    h2[t] = 0.25f * s;
}

// C3 sparse-connected conv 5x5 (6->16) + ReLU + 2x2 avgpool, fused.
__global__ __launch_bounds__(256) void c3_s4_kernel(const float* __restrict__ h2,
        const float* __restrict__ W3, const float* __restrict__ b3,
        float* __restrict__ h4) {
    const unsigned char MASK[16] = {7,14,28,56,49,35,15,30,60,57,51,39,27,54,45,63};
    int t = blockIdx.x * 256 + threadIdx.x;
    const int total = 16 * P2 * P2;
    if (t >= total) return;
    int o  = t / (P2 * P2);
    int r  = t % (P2 * P2);
    int y  = r / P2, x0 = r % P2;

    float a00, a01, a10, a11;
    a00 = a01 = a10 = a11 = b3[o];
    unsigned m = MASK[o];

    for (int i = 0; i < 6; ++i) {
        if (!((m >> i) & 1)) continue;
        const float2* hp2 = (const float2*)(h2 + i * P1 * P1 + (2 * y) * P1 + 2 * x0);
        const float* wp = W3 + (o * 6 + i) * 25;
        float w[25];
        #pragma unroll
        for (int k = 0; k < 25; ++k) w[k] = wp[k];
        float p[6][6];
        #pragma unroll
        for (int ii = 0; ii < 6; ++ii) {
            float2 a0 = hp2[ii * 127 + 0];
            float2 a1 = hp2[ii * 127 + 1];
            float2 a2 = hp2[ii * 127 + 2];
            p[ii][0] = a0.x; p[ii][1] = a0.y; p[ii][2] = a1.x;
            p[ii][3] = a1.y; p[ii][4] = a2.x; p[ii][5] = a2.y;
        }
        #pragma unroll
        for (int kh = 0; kh < 5; ++kh)
            #pragma unroll
            for (int kw = 0; kw < 5; ++kw) {
                float wv = w[kh * 5 + kw];
                a00 = fmaf(p[kh][kw],         wv, a00);
                a01 = fmaf(p[kh][kw + 1],     wv, a01);
                a10 = fmaf(p[kh + 1][kw],     wv, a10);
                a11 = fmaf(p[kh + 1][kw + 1], wv, a11);
            }
    }
    h4[t] = 0.25f * (fmaxf(a00, 0.f) + fmaxf(a01, 0.f) + fmaxf(a10, 0.f) + fmaxf(a11, 0.f));
}

__device__ __forceinline__ float block_reduce_256(float v) {
    #pragma unroll
    for (int off = 32; off > 0; off >>= 1) v += __shfl_down(v, off, 64);
    __shared__ float s[4];
    int lane = threadIdx.x & 63, wv = threadIdx.x >> 6;
    if (lane == 0) s[wv] = v;
    __syncthreads();
    return s[0] + s[1] + s[2] + s[3];
}

// C5: 120 dot-products of length 250000 (flattened layouts match). Split-K.
__global__ __launch_bounds__(256) void c5_kernel(const float* __restrict__ h4,
        const float* __restrict__ W5, float* __restrict__ c5acc) {
    int row = blockIdx.y;
    const float4* wr = (const float4*)(W5 + (size_t)row * C5_K);
    const float4* hv = (const float4*)h4;
    int start = blockIdx.x * C5_CHUNK_F4;
    int end   = start + C5_CHUNK_F4;
    float s = 0.f;
    for (int i = start + (int)threadIdx.x; i < end; i += 256) {
        float4 w = wr[i], h = hv[i];
        s = fmaf(w.x, h.x, s); s = fmaf(w.y, h.y, s);
        s = fmaf(w.z, h.z, s); s = fmaf(w.w, h.w, s);
    }
    s = block_reduce_256(s);
    if (threadIdx.x == 0) atomicAdd(&c5acc[row], s);
}

// F6+F7 fused: each block computes 128 h6 values (W6 staged in LDS), then the
// partial dot of those 128 values against W7's matching column slice for all
// 54 outputs. Last-arriving block reduces the 768x54 partials and writes out.
// Decoupled last-block pattern: no spin-wait, no co-residency requirement.
__global__ __launch_bounds__(256) void f6f7_kernel(const float* __restrict__ c5acc,
        const float* __restrict__ W6, const float* __restrict__ b6,
        const float* __restrict__ W7, const float* __restrict__ b7,
        float* __restrict__ part, unsigned int* __restrict__ counter,
        float* __restrict__ out) {
    __shared__ float ws6[F6_RPB * F6_STRIDE];  // 63488 B
    __shared__ float h5s[120];
    __shared__ float h6s[F6_RPB];
    __shared__ unsigned int lastflag;
    int tid = threadIdx.x;
    int base = blockIdx.x * F6_RPB;
    if (tid < 120) h5s[tid] = fmaxf(c5acc[tid], 0.f);
    const float4* src = (const float4*)(W6 + (size_t)base * 120);
    #pragma unroll
    for (int i = 0; i < 15; ++i) {
        int f4 = tid + i * 256;            // 0..3839
        float4 v = src[f4];
        int flat = f4 * 4;
        int row = flat / 120;
        int col = flat - row * 120;        // multiple of 4
        *(float4*)&ws6[row * F6_STRIDE + col] = v;
    }
    __syncthreads();
    {
        int row  = tid >> 1;
        int half = tid & 1;
        const float4* wr4 = (const float4*)&ws6[row * F6_STRIDE + half * 60];
        const float4* hh4 = (const float4*)&h5s[half * 60];
        float a = 0.f;
        #pragma unroll
        for (int j = 0; j < 15; ++j) {
            float4 w = wr4[j], h = hh4[j];
            a = fmaf(w.x, h.x, a); a = fmaf(w.y, h.y, a);
            a = fmaf(w.z, h.z, a); a = fmaf(w.w, h.w, a);
        }
        a += __shfl_xor(a, 1, 64);
        if (half == 0) h6s[row] = fmaxf(a + b6[base + row], 0.f);
    }
    __syncthreads();
    // F7 partials: wave w handles outputs o = w, w+4, ...
    {
        int wv = tid >> 6, lane = tid & 63;
        for (int o = wv; o < 54; o += 4) {
            const float* w7r = W7 + (size_t)o * F6_OUT + base;
            float p = fmaf(w7r[lane], h6s[lane], w7r[lane + 64] * h6s[lane + 64]);
            #pragma unroll
            for (int off = 32; off > 0; off >>= 1) p += __shfl_down(p, off, 64);
            if (lane == 0) part[(size_t)blockIdx.x * 64 + o] = p;
        }
    }
    __threadfence();   // release: make partials device-visible
    __syncthreads();
    if (tid == 0) {
        unsigned int old = atomicAdd(counter, 1u);
        lastflag = (old == F6_NBLK - 1) ? 1u : 0u;
    }
    __syncthreads();
    if (!lastflag) return;
    __threadfence();   // acquire side
    if (tid < 216) {   // 54 outputs x 4 partial-summers
        int o = tid >> 2, q = tid & 3;
        float s = 0.f;
        for (int b = q; b < F6_NBLK; b += 4)
            s += part[(size_t)b * 64 + o];
        s += __shfl_down(s, 1, 64);
        s += __shfl_down(s, 2, 64);
        if (q == 0) out[o] = b7[o] + s;
    }
}

extern "C" void kernel_launch(void* const* d_in, const int* in_sizes, int n_in,
                              void* d_out, int out_size, void* d_ws, size_t ws_size,
                              hipStream_t stream) {
    const float* x  = (const float*)d_in[0];
    const float* W1 = (const float*)d_in[1];
    const float* b1 = (const float*)d_in[2];
    const float* W3 = (const float*)d_in[3];
    const float* b3 = (const float*)d_in[4];
    const float* W5 = (const float*)d_in[5];
    const float* b5 = (const float*)d_in[6];
    const float* W6 = (const float*)d_in[7];
    const float* b6 = (const float*)d_in[8];
    const float* W7 = (const float*)d_in[9];
    const float* b7 = (const float*)d_in[10];
    float* out = (float*)d_out;
    float* ws  = (float*)d_ws;

    float* h2 = ws + WS_H2;
    float* h4 = ws + WS_H4;
    float* c5 = ws + WS_C5;
    float* part = ws + WS_PART;
    unsigned int* counter = (unsigned int*)(ws + WS_CNT);

    {
        int total = 6 * P1 * P1;
        c1_s2_kernel<<<(total + 255) / 256, 256, 0, stream>>>(x, W1, b1, h2, b5, c5, counter);
    }
    {
        int total = 16 * P2 * P2;
        c3_s4_kernel<<<(total + 255) / 256, 256, 0, stream>>>(h2, W3, b3, h4);
    }
    c5_kernel<<<dim3(C5_K4 / C5_CHUNK_F4, 120), 256, 0, stream>>>(h4, W5, c5);
    f6f7_kernel<<<F6_NBLK, 256, 0, stream>>>(c5, W6, b6, W7, b7, part, counter, out);
}

// Round 5
// 282.291 us; speedup vs baseline: 1.4133x; 1.4133x over previous
//
#include <hip/hip_runtime.h>

#define P1 254   // pooled size after C1+S2
#define P2 125   // pooled size after C3+S4
#define C5_K 250000           // 16*125*125
#define C5_K4 62500           // in float4
#define C5_CHUNK_F4 2500      // 25 chunks per row
#define F6_OUT 98304
#define F7_K4 24576           // 98304/4
#define F7_CHUNK_F4 1024      // 24 chunks

// ---- ws layout (floats) ----
#define WS_H2 0        // 6*254*254 = 387096
#define WS_H4 400000   // 16*125*125 = 250000
#define WS_C5 650000   // 120
#define WS_H6 650128   // 98304

// C1 conv 5x5 (1->6) + ReLU + 2x2 avgpool, fused. One thread per pooled output.
// Block 0 also seeds the c5 accumulator (b5) and the output accumulator (b7).
__global__ __launch_bounds__(256) void c1_s2_kernel(const float* __restrict__ x,
        const float* __restrict__ W1, const float* __restrict__ b1,
        float* __restrict__ h2,
        const float* __restrict__ b5, const float* __restrict__ b7,
        float* __restrict__ c5acc, float* __restrict__ out) {
    if (blockIdx.x == 0) {
        int t = threadIdx.x;
        if (t < 120) c5acc[t] = b5[t];
        if (t >= 128 && t < 182) out[t - 128] = b7[t - 128];
    }
    int t = blockIdx.x * 256 + threadIdx.x;
    const int total = 6 * P1 * P1;
    if (t >= total) return;
    int c  = t / (P1 * P1);
    int r  = t % (P1 * P1);
    int y  = r / P1, x0 = r % P1;

    float w[25];
    #pragma unroll
    for (int k = 0; k < 25; ++k) w[k] = W1[c * 25 + k];

    float p[6][6];
    const float2* xin2 = (const float2*)(x + (2 * y) * 512 + 2 * x0);  // 8B-aligned
    #pragma unroll
    for (int i = 0; i < 6; ++i) {
        float2 a0 = xin2[i * 256 + 0];
        float2 a1 = xin2[i * 256 + 1];
        float2 a2 = xin2[i * 256 + 2];
        p[i][0] = a0.x; p[i][1] = a0.y; p[i][2] = a1.x;
        p[i][3] = a1.y; p[i][4] = a2.x; p[i][5] = a2.y;
    }

    float bias = b1[c];
    float s = 0.f;
    #pragma unroll
    for (int dy = 0; dy < 2; ++dy)
        #pragma unroll
        for (int dx = 0; dx < 2; ++dx) {
            float a = bias;
            #pragma unroll
            for (int kh = 0; kh < 5; ++kh)
                #pragma unroll
                for (int kw = 0; kw < 5; ++kw)
                    a = fmaf(p[dy + kh][dx + kw], w[kh * 5 + kw], a);
            s += fmaxf(a, 0.f);
        }
    h2[t] = 0.25f * s;
}

// C3 sparse-connected conv 5x5 (6->16) + ReLU + 2x2 avgpool, fused.
__global__ __launch_bounds__(256) void c3_s4_kernel(const float* __restrict__ h2,
        const float* __restrict__ W3, const float* __restrict__ b3,
        float* __restrict__ h4) {
    const unsigned char MASK[16] = {7,14,28,56,49,35,15,30,60,57,51,39,27,54,45,63};
    int t = blockIdx.x * 256 + threadIdx.x;
    const int total = 16 * P2 * P2;
    if (t >= total) return;
    int o  = t / (P2 * P2);
    int r  = t % (P2 * P2);
    int y  = r / P2, x0 = r % P2;

    float a00, a01, a10, a11;
    a00 = a01 = a10 = a11 = b3[o];
    unsigned m = MASK[o];

    for (int i = 0; i < 6; ++i) {
        if (!((m >> i) & 1)) continue;
        const float2* hp2 = (const float2*)(h2 + i * P1 * P1 + (2 * y) * P1 + 2 * x0);
        const float* wp = W3 + (o * 6 + i) * 25;
        float w[25];
        #pragma unroll
        for (int k = 0; k < 25; ++k) w[k] = wp[k];
        float p[6][6];
        #pragma unroll
        for (int ii = 0; ii < 6; ++ii) {
            float2 a0 = hp2[ii * 127 + 0];
            float2 a1 = hp2[ii * 127 + 1];
            float2 a2 = hp2[ii * 127 + 2];
            p[ii][0] = a0.x; p[ii][1] = a0.y; p[ii][2] = a1.x;
            p[ii][3] = a1.y; p[ii][4] = a2.x; p[ii][5] = a2.y;
        }
        #pragma unroll
        for (int kh = 0; kh < 5; ++kh)
            #pragma unroll
            for (int kw = 0; kw < 5; ++kw) {
                float wv = w[kh * 5 + kw];
                a00 = fmaf(p[kh][kw],         wv, a00);
                a01 = fmaf(p[kh][kw + 1],     wv, a01);
                a10 = fmaf(p[kh + 1][kw],     wv, a10);
                a11 = fmaf(p[kh + 1][kw + 1], wv, a11);
            }
    }
    h4[t] = 0.25f * (fmaxf(a00, 0.f) + fmaxf(a01, 0.f) + fmaxf(a10, 0.f) + fmaxf(a11, 0.f));
}

__device__ __forceinline__ float block_reduce_256(float v) {
    #pragma unroll
    for (int off = 32; off > 0; off >>= 1) v += __shfl_down(v, off, 64);
    __shared__ float s[4];
    int lane = threadIdx.x & 63, wv = threadIdx.x >> 6;
    if (lane == 0) s[wv] = v;
    __syncthreads();
    return s[0] + s[1] + s[2] + s[3];
}

// C5: 120 dot-products of length 250000 (flattened layouts match). Split-K.
__global__ __launch_bounds__(256) void c5_kernel(const float* __restrict__ h4,
        const float* __restrict__ W5, float* __restrict__ c5acc) {
    int row = blockIdx.y;
    const float4* wr = (const float4*)(W5 + (size_t)row * C5_K);
    const float4* hv = (const float4*)h4;
    int start = blockIdx.x * C5_CHUNK_F4;
    int end   = start + C5_CHUNK_F4;
    float s = 0.f;
    for (int i = start + (int)threadIdx.x; i < end; i += 256) {
        float4 w = wr[i], h = hv[i];
        s = fmaf(w.x, h.x, s); s = fmaf(w.y, h.y, s);
        s = fmaf(w.z, h.z, s); s = fmaf(w.w, h.w, s);
    }
    s = block_reduce_256(s);
    if (threadIdx.x == 0) atomicAdd(&c5acc[row], s);
}

// F6: h6 = relu(W6 @ relu(c5) + b6).
// Block stages 128 rows of W6 (62 KB, padded stride) into LDS with coalesced
// float4 loads; 2 threads per row compute the dot from LDS.
#define F6_RPB 128
#define F6_STRIDE 124
__global__ __launch_bounds__(256) void f6_kernel(const float* __restrict__ c5acc,
        const float* __restrict__ W6, const float* __restrict__ b6,
        float* __restrict__ h6) {
    __shared__ float ws6[F6_RPB * F6_STRIDE];  // 63488 B
    __shared__ float h5s[120];
    int tid = threadIdx.x;
    int base = blockIdx.x * F6_RPB;
    if (tid < 120) h5s[tid] = fmaxf(c5acc[tid], 0.f);
    const float4* src = (const float4*)(W6 + (size_t)base * 120);
    #pragma unroll
    for (int i = 0; i < 15; ++i) {
        int f4 = tid + i * 256;            // 0..3839
        float4 v = src[f4];
        int flat = f4 * 4;
        int row = flat / 120;
        int col = flat - row * 120;        // multiple of 4
        *(float4*)&ws6[row * F6_STRIDE + col] = v;
    }
    __syncthreads();
    int row  = tid >> 1;
    int half = tid & 1;
    const float4* wr4 = (const float4*)&ws6[row * F6_STRIDE + half * 60];
    const float4* hh4 = (const float4*)&h5s[half * 60];
    float a = 0.f;
    #pragma unroll
    for (int j = 0; j < 15; ++j) {
        float4 w = wr4[j], h = hh4[j];
        a = fmaf(w.x, h.x, a); a = fmaf(w.y, h.y, a);
        a = fmaf(w.z, h.z, a); a = fmaf(w.w, h.w, a);
    }
    a += __shfl_xor(a, 1, 64);
    if (half == 0) {
        int o = base + row;
        h6[o] = fmaxf(a + b6[o], 0.f);
    }
}

// F7: out = h6 @ W7.T + b7 (bias pre-seeded by c1 block 0). Split-K + atomics.
__global__ __launch_bounds__(256) void f7_kernel(const float* __restrict__ h6,
        const float* __restrict__ W7, float* __restrict__ out) {
    int row = blockIdx.y;
    const float4* wr = (const float4*)(W7 + (size_t)row * (F7_K4 * 4));
    const float4* hv = (const float4*)h6;
    int start = blockIdx.x * F7_CHUNK_F4;
    int end   = start + F7_CHUNK_F4;
    float s = 0.f;
    for (int i = start + (int)threadIdx.x; i < end; i += 256) {
        float4 w = wr[i], h = hv[i];
        s = fmaf(w.x, h.x, s); s = fmaf(w.y, h.y, s);
        s = fmaf(w.z, h.z, s); s = fmaf(w.w, h.w, s);
    }
    s = block_reduce_256(s);
    if (threadIdx.x == 0) atomicAdd(&out[row], s);
}

extern "C" void kernel_launch(void* const* d_in, const int* in_sizes, int n_in,
                              void* d_out, int out_size, void* d_ws, size_t ws_size,
                              hipStream_t stream) {
    const float* x  = (const float*)d_in[0];
    const float* W1 = (const float*)d_in[1];
    const float* b1 = (const float*)d_in[2];
    const float* W3 = (const float*)d_in[3];
    const float* b3 = (const float*)d_in[4];
    const float* W5 = (const float*)d_in[5];
    const float* b5 = (const float*)d_in[6];
    const float* W6 = (const float*)d_in[7];
    const float* b6 = (const float*)d_in[8];
    const float* W7 = (const float*)d_in[9];
    const float* b7 = (const float*)d_in[10];
    float* out = (float*)d_out;
    float* ws  = (float*)d_ws;

    float* h2 = ws + WS_H2;
    float* h4 = ws + WS_H4;
    float* c5 = ws + WS_C5;
    float* h6 = ws + WS_H6;

    {
        int total = 6 * P1 * P1;
        c1_s2_kernel<<<(total + 255) / 256, 256, 0, stream>>>(x, W1, b1, h2, b5, b7, c5, out);
    }
    {
        int total = 16 * P2 * P2;
        c3_s4_kernel<<<(total + 255) / 256, 256, 0, stream>>>(h2, W3, b3, h4);
    }
    c5_kernel<<<dim3(C5_K4 / C5_CHUNK_F4, 120), 256, 0, stream>>>(h4, W5, c5);
    f6_kernel<<<F6_OUT / F6_RPB, 256, 0, stream>>>(c5, W6, b6, h6);
    f7_kernel<<<dim3(F7_K4 / F7_CHUNK_F4, 54), 256, 0, stream>>>(h6, W7, out);
}

// Round 6
// 273.212 us; speedup vs baseline: 1.4603x; 1.0332x over previous
//
#include <hip/hip_runtime.h>

typedef float f32x4 __attribute__((ext_vector_type(4)));

#define P1 254   // pooled size after C1+S2
#define P2 125   // pooled size after C3+S4
#define C5_K 250000           // 16*125*125
#define C5_K4 62500           // in float4
#define C5_CHUNK_F4 5000      // 12.5 chunks -> 13? no: 62500/5000 = 12.5 ... use 2500*2
#undef C5_CHUNK_F4
#define C5_CHUNK_F4 3125      // 20 chunks per row, 2400 blocks
#define F6_OUT 98304
#define F7_K4 24576           // 98304/4
#define F7_CHUNK_F4 2048      // 12 chunks

// ---- ws layout (floats) ----
#define WS_H2 0        // 6*254*254 = 387096
#define WS_H4 400000   // 16*125*125 = 250000
#define WS_C5 650000   // 120
#define WS_H6 650128   // 98304

__device__ __forceinline__ float4 nt_load4(const float4* p) {
    f32x4 v = __builtin_nontemporal_load((const f32x4*)p);
    return make_float4(v.x, v.y, v.z, v.w);
}

// C1 conv 5x5 (1->6) + ReLU + 2x2 avgpool, fused. One thread per pooled output.
// Block 0 also seeds the c5 accumulator (b5) and the output accumulator (b7).
__global__ __launch_bounds__(256) void c1_s2_kernel(const float* __restrict__ x,
        const float* __restrict__ W1, const float* __restrict__ b1,
        float* __restrict__ h2,
        const float* __restrict__ b5, const float* __restrict__ b7,
        float* __restrict__ c5acc, float* __restrict__ out) {
    if (blockIdx.x == 0) {
        int t = threadIdx.x;
        if (t < 120) c5acc[t] = b5[t];
        if (t >= 128 && t < 182) out[t - 128] = b7[t - 128];
    }
    int t = blockIdx.x * 256 + threadIdx.x;
    const int total = 6 * P1 * P1;
    if (t >= total) return;
    int c  = t / (P1 * P1);
    int r  = t % (P1 * P1);
    int y  = r / P1, x0 = r % P1;

    float w[25];
    #pragma unroll
    for (int k = 0; k < 25; ++k) w[k] = W1[c * 25 + k];

    float p[6][6];
    const float2* xin2 = (const float2*)(x + (2 * y) * 512 + 2 * x0);  // 8B-aligned
    #pragma unroll
    for (int i = 0; i < 6; ++i) {
        float2 a0 = xin2[i * 256 + 0];
        float2 a1 = xin2[i * 256 + 1];
        float2 a2 = xin2[i * 256 + 2];
        p[i][0] = a0.x; p[i][1] = a0.y; p[i][2] = a1.x;
        p[i][3] = a1.y; p[i][4] = a2.x; p[i][5] = a2.y;
    }

    float bias = b1[c];
    float s = 0.f;
    #pragma unroll
    for (int dy = 0; dy < 2; ++dy)
        #pragma unroll
        for (int dx = 0; dx < 2; ++dx) {
            float a = bias;
            #pragma unroll
            for (int kh = 0; kh < 5; ++kh)
                #pragma unroll
                for (int kw = 0; kw < 5; ++kw)
                    a = fmaf(p[dy + kh][dx + kw], w[kh * 5 + kw], a);
            s += fmaxf(a, 0.f);
        }
    h2[t] = 0.25f * s;
}

// C3 sparse-connected conv 5x5 (6->16) + ReLU + 2x2 avgpool, fused.
__global__ __launch_bounds__(256) void c3_s4_kernel(const float* __restrict__ h2,
        const float* __restrict__ W3, const float* __restrict__ b3,
        float* __restrict__ h4) {
    const unsigned char MASK[16] = {7,14,28,56,49,35,15,30,60,57,51,39,27,54,45,63};
    int t = blockIdx.x * 256 + threadIdx.x;
    const int total = 16 * P2 * P2;
    if (t >= total) return;
    int o  = t / (P2 * P2);
    int r  = t % (P2 * P2);
    int y  = r / P2, x0 = r % P2;

    float a00, a01, a10, a11;
    a00 = a01 = a10 = a11 = b3[o];
    unsigned m = MASK[o];

    for (int i = 0; i < 6; ++i) {
        if (!((m >> i) & 1)) continue;
        const float2* hp2 = (const float2*)(h2 + i * P1 * P1 + (2 * y) * P1 + 2 * x0);
        const float* wp = W3 + (o * 6 + i) * 25;
        float w[25];
        #pragma unroll
        for (int k = 0; k < 25; ++k) w[k] = wp[k];
        float p[6][6];
        #pragma unroll
        for (int ii = 0; ii < 6; ++ii) {
            float2 a0 = hp2[ii * 127 + 0];
            float2 a1 = hp2[ii * 127 + 1];
            float2 a2 = hp2[ii * 127 + 2];
            p[ii][0] = a0.x; p[ii][1] = a0.y; p[ii][2] = a1.x;
            p[ii][3] = a1.y; p[ii][4] = a2.x; p[ii][5] = a2.y;
        }
        #pragma unroll
        for (int kh = 0; kh < 5; ++kh)
            #pragma unroll
            for (int kw = 0; kw < 5; ++kw) {
                float wv = w[kh * 5 + kw];
                a00 = fmaf(p[kh][kw],         wv, a00);
                a01 = fmaf(p[kh][kw + 1],     wv, a01);
                a10 = fmaf(p[kh + 1][kw],     wv, a10);
                a11 = fmaf(p[kh + 1][kw + 1], wv, a11);
            }
    }
    h4[t] = 0.25f * (fmaxf(a00, 0.f) + fmaxf(a01, 0.f) + fmaxf(a10, 0.f) + fmaxf(a11, 0.f));
}

__device__ __forceinline__ float block_reduce_256(float v) {
    #pragma unroll
    for (int off = 32; off > 0; off >>= 1) v += __shfl_down(v, off, 64);
    __shared__ float s[4];
    int lane = threadIdx.x & 63, wv = threadIdx.x >> 6;
    if (lane == 0) s[wv] = v;
    __syncthreads();
    return s[0] + s[1] + s[2] + s[3];
}

// C5: 120 dot-products of length 250000 (flattened layouts match). Split-K.
// W5 is streamed once -> nontemporal; h4 is reused 120x -> normal (L2/L3 resident).
__global__ __launch_bounds__(256) void c5_kernel(const float* __restrict__ h4,
        const float* __restrict__ W5, float* __restrict__ c5acc) {
    int row = blockIdx.y;
    const float4* wr = (const float4*)(W5 + (size_t)row * C5_K);
    const float4* hv = (const float4*)h4;
    int start = blockIdx.x * C5_CHUNK_F4;
    int end   = start + C5_CHUNK_F4;
    float s = 0.f;
    for (int i = start + (int)threadIdx.x; i < end; i += 256) {
        float4 w = nt_load4(&wr[i]);
        float4 h = hv[i];
        s = fmaf(w.x, h.x, s); s = fmaf(w.y, h.y, s);
        s = fmaf(w.z, h.z, s); s = fmaf(w.w, h.w, s);
    }
    s = block_reduce_256(s);
    if (threadIdx.x == 0) atomicAdd(&c5acc[row], s);
}

// F6: h6 = relu(W6 @ relu(c5) + b6).
// Block stages 128 rows of W6 (62 KB, padded stride) into LDS with coalesced
// nontemporal float4 loads; 2 threads per row compute the dot from LDS.
#define F6_RPB 128
#define F6_STRIDE 124
__global__ __launch_bounds__(256) void f6_kernel(const float* __restrict__ c5acc,
        const float* __restrict__ W6, const float* __restrict__ b6,
        float* __restrict__ h6) {
    __shared__ float ws6[F6_RPB * F6_STRIDE];  // 63488 B
    __shared__ float h5s[120];
    int tid = threadIdx.x;
    int base = blockIdx.x * F6_RPB;
    if (tid < 120) h5s[tid] = fmaxf(c5acc[tid], 0.f);
    const float4* src = (const float4*)(W6 + (size_t)base * 120);
    #pragma unroll
    for (int i = 0; i < 15; ++i) {
        int f4 = tid + i * 256;            // 0..3839
        float4 v = nt_load4(&src[f4]);
        int flat = f4 * 4;
        int row = flat / 120;
        int col = flat - row * 120;        // multiple of 4
        *(float4*)&ws6[row * F6_STRIDE + col] = v;
    }
    __syncthreads();
    int row  = tid >> 1;
    int half = tid & 1;
    const float4* wr4 = (const float4*)&ws6[row * F6_STRIDE + half * 60];
    const float4* hh4 = (const float4*)&h5s[half * 60];
    float a = 0.f;
    #pragma unroll
    for (int j = 0; j < 15; ++j) {
        float4 w = wr4[j], h = hh4[j];
        a = fmaf(w.x, h.x, a); a = fmaf(w.y, h.y, a);
        a = fmaf(w.z, h.z, a); a = fmaf(w.w, h.w, a);
    }
    a += __shfl_xor(a, 1, 64);
    if (half == 0) {
        int o = base + row;
        h6[o] = fmaxf(a + b6[o], 0.f);
    }
}

// F7: out = h6 @ W7.T + b7 (bias pre-seeded by c1 block 0). Split-K + atomics.
__global__ __launch_bounds__(256) void f7_kernel(const float* __restrict__ h6,
        const float* __restrict__ W7, float* __restrict__ out) {
    int row = blockIdx.y;
    const float4* wr = (const float4*)(W7 + (size_t)row * (F7_K4 * 4));
    const float4* hv = (const float4*)h6;
    int start = blockIdx.x * F7_CHUNK_F4;
    int end   = start + F7_CHUNK_F4;
    float s = 0.f;
    for (int i = start + (int)threadIdx.x; i < end; i += 256) {
        float4 w = nt_load4(&wr[i]);
        float4 h = hv[i];
        s = fmaf(w.x, h.x, s); s = fmaf(w.y, h.y, s);
        s = fmaf(w.z, h.z, s); s = fmaf(w.w, h.w, s);
    }
    s = block_reduce_256(s);
    if (threadIdx.x == 0) atomicAdd(&out[row], s);
}

extern "C" void kernel_launch(void* const* d_in, const int* in_sizes, int n_in,
                              void* d_out, int out_size, void* d_ws, size_t ws_size,
                              hipStream_t stream) {
    const float* x  = (const float*)d_in[0];
    const float* W1 = (const float*)d_in[1];
    const float* b1 = (const float*)d_in[2];
    const float* W3 = (const float*)d_in[3];
    const float* b3 = (const float*)d_in[4];
    const float* W5 = (const float*)d_in[5];
    const float* b5 = (const float*)d_in[6];
    const float* W6 = (const float*)d_in[7];
    const float* b6 = (const float*)d_in[8];
    const float* W7 = (const float*)d_in[9];
    const float* b7 = (const float*)d_in[10];
    float* out = (float*)d_out;
    float* ws  = (float*)d_ws;

    float* h2 = ws + WS_H2;
    float* h4 = ws + WS_H4;
    float* c5 = ws + WS_C5;
    float* h6 = ws + WS_H6;

    {
        int total = 6 * P1 * P1;
        c1_s2_kernel<<<(total + 255) / 256, 256, 0, stream>>>(x, W1, b1, h2, b5, b7, c5, out);
    }
    {
        int total = 16 * P2 * P2;
        c3_s4_kernel<<<(total + 255) / 256, 256, 0, stream>>>(h2, W3, b3, h4);
    }
    c5_kernel<<<dim3(C5_K4 / C5_CHUNK_F4, 120), 256, 0, stream>>>(h4, W5, c5);
    f6_kernel<<<F6_OUT / F6_RPB, 256, 0, stream>>>(c5, W6, b6, h6);
    f7_kernel<<<dim3(F7_K4 / F7_CHUNK_F4, 54), 256, 0, stream>>>(h6, W7, out);
}